// Round 4
// baseline (125.106 us; speedup 1.0000x reference)
//
#include <hip/hip_runtime.h>
#include <hip/hip_bf16.h>

// MMD loss via bf16 hi/lo-split MFMA Gram pass, 256^2-tile 8-wave pipelined.
//   dot(x_i,x_j) ~= hi.hi + hi.lo + lo.hi  (3 planes, K_eff=768, BK=64 -> 12 K-tiles)
//   d2 = sq_i + sq_j - 2 dot;  kernels = u+u^2+u^4+u^8+u^16, u=2^(negc*d2)
// T2: LDS col-slot XOR-swizzle (slot ^= row&7), pre-swizzled global src (rule #21).
// T3-min: dbuf, stage t+1 before compute t, one vmcnt(0)+barrier per K-tile.
// T5: setprio(1) around MFMA clusters.  T1: XCD swizzle (528 % 8 == 0).

#define N_TOTAL 8192
#define B_HALF 4096
#define D_DIM 256
#define TILE 256
#define NTILE 32          // 8192/256
#define NTRI 528          // 32*33/2
#define BK 64

typedef float f32x4 __attribute__((ext_vector_type(4)));
typedef short s16x8 __attribute__((ext_vector_type(8)));

__device__ __forceinline__ const float* row_base(const float* src, const float* tgt, int r) {
    return (r < B_HALF) ? src + (size_t)r * D_DIM : tgt + (size_t)(r - B_HALF) * D_DIM;
}

// fused split (hi/lo bf16) + row sq. one wave per row, 4 rows/block.
__global__ __launch_bounds__(256) void prep_kernel(const float* __restrict__ src,
                                                   const float* __restrict__ tgt,
                                                   ushort* __restrict__ hi,
                                                   ushort* __restrict__ lo,
                                                   float* __restrict__ sq) {
    int w = threadIdx.x >> 6, lane = threadIdx.x & 63;
    int row = blockIdx.x * 4 + w;
    const float* rp = row_base(src, tgt, row);
    float4 v = ((const float4*)rp)[lane];
    float f[4] = {v.x, v.y, v.z, v.w};
    ushort h[4], l[4];
    #pragma unroll
    for (int e = 0; e < 4; ++e) {
        __hip_bfloat16 hb = __float2bfloat16(f[e]);
        float hf = __bfloat162float(hb);
        __hip_bfloat16 lb = __float2bfloat16(f[e] - hf);
        h[e] = *(ushort*)&hb;
        l[e] = *(ushort*)&lb;
    }
    size_t base = (size_t)row * D_DIM + lane * 4;
    *(ushort4*)(hi + base) = *(ushort4*)h;
    *(ushort4*)(lo + base) = *(ushort4*)l;
    float s = f[0]*f[0] + f[1]*f[1] + f[2]*f[2] + f[3]*f[3];
    #pragma unroll
    for (int off = 32; off; off >>= 1) s += __shfl_down(s, off, 64);
    if (lane == 0) sq[row] = s;
}

// per-block partial column sums (no atomics)
__global__ __launch_bounds__(256) void colpart_kernel(const float* __restrict__ src,
                                                      const float* __restrict__ tgt,
                                                      float* __restrict__ colpart) {
    int t  = threadIdx.x;
    int r0 = blockIdx.x * 128;
    float s = 0.f;
    for (int r = r0; r < r0 + 128; ++r)
        s += row_base(src, tgt, r)[t];
    colpart[blockIdx.x * D_DIM + t] = s;
}

__global__ __launch_bounds__(256) void bw_kernel(const float* __restrict__ sq,
                                                 const float* __restrict__ colpart,
                                                 float* __restrict__ negc,
                                                 double* __restrict__ accum) {
    __shared__ double red[256];
    int t = threadIdx.x;
    double s = 0.0;
    for (int i = t; i < N_TOTAL; i += 256) s += (double)sq[i];
    red[t] = s;
    __syncthreads();
    for (int off = 128; off; off >>= 1) {
        if (t < off) red[t] += red[t + off];
        __syncthreads();
    }
    double sumsq = red[0];
    __syncthreads();
    float c = 0.f;
    for (int k = 0; k < 64; ++k) c += colpart[k * D_DIM + t];
    red[t] = (double)c * (double)c;
    __syncthreads();
    for (int off = 128; off; off >>= 1) {
        if (t < off) red[t] += red[t + off];
        __syncthreads();
    }
    if (t == 0) {
        double S1 = 2.0 * (double)N_TOTAL * sumsq - 2.0 * red[0];
        double nn = (double)N_TOTAL * (double)N_TOTAL - (double)N_TOTAL;
        double bw = S1 / nn / 4.0;    // KERNEL_MUL^(KERNEL_NUM//2) = 4
        negc[0] = (float)(-1.4426950408889634 / (16.0 * bw));
        accum[0] = 0.0;
    }
}

__device__ __forceinline__ void gload_lds16(const void* g, void* l) {
    __builtin_amdgcn_global_load_lds((const __attribute__((address_space(1))) unsigned int*)g,
                                     (__attribute__((address_space(3))) unsigned int*)l,
                                     16, 0, 0);
}

__global__ __launch_bounds__(512, 2) void mmd_mfma(const ushort* __restrict__ hi,
                                                   const ushort* __restrict__ lo,
                                                   const float* __restrict__ sq,
                                                   const float* __restrict__ negc,
                                                   double* __restrict__ accum) {
    __shared__ ushort As[2][TILE * BK];   // 2 x 32 KB
    __shared__ ushort Bs[2][TILE * BK];   // 2 x 32 KB  (total 128 KB)
    __shared__ float wsum[8];

    // T1: XCD-aware swizzle, then triangle decode (jt >= it)
    int b  = blockIdx.x;
    int bs = (b & 7) * (NTRI / 8) + (b >> 3);
    int it = 0, cum = 0;
    while (cum + (NTILE - it) <= bs) { cum += NTILE - it; ++it; }
    int jt = it + (bs - cum);

    int tid = threadIdx.x, lane = tid & 63, wid = tid >> 6;
    int wrow = wid >> 2, wcol = wid & 3;      // 2 x 4 wave grid; per-wave 128x64
    int rowA = it * TILE, rowB = jt * TILE;
    int rsel = lane & 15, ksel = lane >> 4;

    const ushort* Ap[3] = {hi, hi, lo};
    const ushort* Bp[3] = {hi, lo, hi};

    f32x4 acc[8][4] = {};

    auto STAGE = [&](int kt, int buf) {
        int p = kt >> 2, kc = (kt & 3) * BK;
        const ushort* Asrc = Ap[p];
        const ushort* Bsrc = Bp[p];
        #pragma unroll
        for (int lg = 0; lg < 4; ++lg) {
            int ci0 = lg * 512 + wid * 64;    // wave-uniform 16B-chunk base
            int ci  = ci0 + lane;
            int r   = ci >> 3;                // tile row 0..255
            int sl  = ci & 7;                 // physical 16B slot 0..7
            int slin = sl ^ (r & 7);          // pre-swizzled global col slot (T2, rule #21)
            gload_lds16(Asrc + (size_t)(rowA + r) * D_DIM + kc + slin * 8,
                        &As[buf][ci0 * 8]);
            gload_lds16(Bsrc + (size_t)(rowB + r) * D_DIM + kc + slin * 8,
                        &Bs[buf][ci0 * 8]);
        }
    };

    // prologue
    STAGE(0, 0);
    asm volatile("s_waitcnt vmcnt(0)" ::: "memory");
    __syncthreads();

    #pragma unroll 1
    for (int kt = 0; kt < 12; ++kt) {
        int buf = kt & 1;
        if (kt + 1 < 12) STAGE(kt + 1, buf ^ 1);   // issue next tile early (T3)
        #pragma unroll
        for (int ks2 = 0; ks2 < 2; ++ks2) {
            s16x8 bf[4];
            #pragma unroll
            for (int n = 0; n < 4; ++n) {
                int r  = wcol * 64 + n * 16 + rsel;
                int sp = (ks2 * 4 + ksel) ^ (r & 7);   // swizzled read (T2)
                bf[n] = *(const s16x8*)&Bs[buf][r * BK + sp * 8];
            }
            #pragma unroll
            for (int mh = 0; mh < 2; ++mh) {
                s16x8 af[4];
                #pragma unroll
                for (int mm = 0; mm < 4; ++mm) {
                    int r  = wrow * 128 + (mh * 4 + mm) * 16 + rsel;
                    int sp = (ks2 * 4 + ksel) ^ (r & 7);
                    af[mm] = *(const s16x8*)&As[buf][r * BK + sp * 8];
                }
                __builtin_amdgcn_s_setprio(1);          // T5
                #pragma unroll
                for (int mm = 0; mm < 4; ++mm)
                    #pragma unroll
                    for (int n = 0; n < 4; ++n)
                        acc[mh * 4 + mm][n] = __builtin_amdgcn_mfma_f32_16x16x32_bf16(
                            af[mm], bf[n], acc[mh * 4 + mm][n], 0, 0, 0);
                __builtin_amdgcn_s_setprio(0);
            }
        }
        asm volatile("s_waitcnt vmcnt(0)" ::: "memory");  // next tile landed (T4 depth-1)
        __syncthreads();
    }

    // fused epilogue: d2 -> 5-kernel sum
    float nc = *negc;
    float sqj[4];
    #pragma unroll
    for (int n = 0; n < 4; ++n)
        sqj[n] = sq[rowB + wcol * 64 + n * 16 + rsel];
    float tsum = 0.f;
    #pragma unroll
    for (int m = 0; m < 8; ++m) {
        #pragma unroll
        for (int r = 0; r < 4; ++r) {
            float si = sq[rowA + wrow * 128 + m * 16 + ksel * 4 + r];
            #pragma unroll
            for (int n = 0; n < 4; ++n) {
                float d2 = fmaxf(si + sqj[n] - 2.0f * acc[m][n][r], 0.f);
                float u  = exp2f(nc * d2);
                float u2 = u * u, u4 = u2 * u2, u8 = u4 * u4;
                tsum += u + u2 + u4 + u8 + u8 * u8;
            }
        }
    }
    float scale = (((it < 16) == (jt < 16)) ? 1.f : -1.f) * ((it == jt) ? 1.f : 2.f);
    tsum *= scale;

    #pragma unroll
    for (int off = 32; off; off >>= 1) tsum += __shfl_down(tsum, off, 64);
    if (lane == 0) wsum[wid] = tsum;
    __syncthreads();
    if (tid == 0) {
        float t = 0.f;
        #pragma unroll
        for (int w = 0; w < 8; ++w) t += wsum[w];
        atomicAdd(accum, (double)t);
    }
}

__global__ void finalize_kernel(const double* __restrict__ accum, float* __restrict__ out) {
    out[0] = (float)(accum[0] / ((double)B_HALF * (double)B_HALF));
}

extern "C" void kernel_launch(void* const* d_in, const int* in_sizes, int n_in,
                              void* d_out, int out_size, void* d_ws, size_t ws_size,
                              hipStream_t stream) {
    const float* src = (const float*)d_in[0];
    const float* tgt = (const float*)d_in[1];
    float* out = (float*)d_out;

    char* ws = (char*)d_ws;
    float*  sq      = (float*)ws;                         // 32 KB
    float*  colpart = (float*)(ws + 32768);               // 64 KB (64 x 256)
    float*  negc    = (float*)(ws + 98304);
    double* accum   = (double*)(ws + 98312);
    ushort* hi      = (ushort*)(ws + 131072);             // 4 MB
    ushort* lo      = (ushort*)(ws + 131072 + (size_t)N_TOTAL * D_DIM * 2);  // 4 MB

    prep_kernel<<<N_TOTAL / 4, 256, 0, stream>>>(src, tgt, hi, lo, sq);
    colpart_kernel<<<64, 256, 0, stream>>>(src, tgt, colpart);
    bw_kernel<<<1, 256, 0, stream>>>(sq, colpart, negc, accum);
    mmd_mfma<<<NTRI, 512, 0, stream>>>(hi, lo, sq, negc, accum);
    finalize_kernel<<<1, 1, 0, stream>>>(accum, out);
}

// Round 5
// 114.813 us; speedup vs baseline: 1.0896x; 1.0896x over previous
//
#include <hip/hip_runtime.h>
#include <hip/hip_bf16.h>

// MMD loss via bf16 hi/lo-split MFMA Gram pass.
//   dot(x_i,x_j) ~= hi.hi + hi.lo + lo.hi  (3 planes, K_eff=768)
//   d2 = sq_i + sq_j - 2 dot;  kernels = u+u^2+u^4+u^8+u^16, u=2^(negc*d2)
// 128^2 tile, 4 waves, BK=32 double-buffer (32 KB LDS -> 4-5 blocks/CU for
// inter-block barrier overlap), T2 swizzle sp=ks^((r>>1)&3) (0 conflicts),
// single vmcnt+barrier per K-step, T1 XCD swizzle (2080%8==0), T5 setprio.

#define N_TOTAL 8192
#define B_HALF 4096
#define D_DIM 256
#define TILE 128
#define NTILE 64          // 8192/128
#define NTRI 2080         // 64*65/2
#define BK 32

typedef float f32x4 __attribute__((ext_vector_type(4)));
typedef short s16x8 __attribute__((ext_vector_type(8)));

__device__ __forceinline__ const float* row_base(const float* src, const float* tgt, int r) {
    return (r < B_HALF) ? src + (size_t)r * D_DIM : tgt + (size_t)(r - B_HALF) * D_DIM;
}

// fused split (hi/lo bf16) + row sq. one wave per row, 4 rows/block.
__global__ __launch_bounds__(256) void prep_kernel(const float* __restrict__ src,
                                                   const float* __restrict__ tgt,
                                                   ushort* __restrict__ hi,
                                                   ushort* __restrict__ lo,
                                                   float* __restrict__ sq) {
    int w = threadIdx.x >> 6, lane = threadIdx.x & 63;
    int row = blockIdx.x * 4 + w;
    const float* rp = row_base(src, tgt, row);
    float4 v = ((const float4*)rp)[lane];
    float f[4] = {v.x, v.y, v.z, v.w};
    ushort h[4], l[4];
    #pragma unroll
    for (int e = 0; e < 4; ++e) {
        __hip_bfloat16 hb = __float2bfloat16(f[e]);
        float hf = __bfloat162float(hb);
        __hip_bfloat16 lb = __float2bfloat16(f[e] - hf);
        h[e] = *(ushort*)&hb;
        l[e] = *(ushort*)&lb;
    }
    size_t base = (size_t)row * D_DIM + lane * 4;
    *(ushort4*)(hi + base) = *(ushort4*)h;
    *(ushort4*)(lo + base) = *(ushort4*)l;
    float s = f[0]*f[0] + f[1]*f[1] + f[2]*f[2] + f[3]*f[3];
    #pragma unroll
    for (int off = 32; off; off >>= 1) s += __shfl_down(s, off, 64);
    if (lane == 0) sq[row] = s;
}

// per-block partial column sums (no atomics)
__global__ __launch_bounds__(256) void colpart_kernel(const float* __restrict__ src,
                                                      const float* __restrict__ tgt,
                                                      float* __restrict__ colpart) {
    int t  = threadIdx.x;
    int r0 = blockIdx.x * 128;
    float s = 0.f;
    for (int r = r0; r < r0 + 128; ++r)
        s += row_base(src, tgt, r)[t];
    colpart[blockIdx.x * D_DIM + t] = s;
}

__global__ __launch_bounds__(256) void bw_kernel(const float* __restrict__ sq,
                                                 const float* __restrict__ colpart,
                                                 float* __restrict__ negc,
                                                 double* __restrict__ accum) {
    __shared__ double red[256];
    int t = threadIdx.x;
    double s = 0.0;
    for (int i = t; i < N_TOTAL; i += 256) s += (double)sq[i];
    red[t] = s;
    __syncthreads();
    for (int off = 128; off; off >>= 1) {
        if (t < off) red[t] += red[t + off];
        __syncthreads();
    }
    double sumsq = red[0];
    __syncthreads();
    float c = 0.f;
    for (int k = 0; k < 64; ++k) c += colpart[k * D_DIM + t];
    red[t] = (double)c * (double)c;
    __syncthreads();
    for (int off = 128; off; off >>= 1) {
        if (t < off) red[t] += red[t + off];
        __syncthreads();
    }
    if (t == 0) {
        double S1 = 2.0 * (double)N_TOTAL * sumsq - 2.0 * red[0];
        double nn = (double)N_TOTAL * (double)N_TOTAL - (double)N_TOTAL;
        double bw = S1 / nn / 4.0;    // KERNEL_MUL^(KERNEL_NUM//2) = 4
        negc[0] = (float)(-1.4426950408889634 / (16.0 * bw));
        accum[0] = 0.0;
    }
}

__device__ __forceinline__ void gload_lds16(const void* g, void* l) {
    __builtin_amdgcn_global_load_lds((const __attribute__((address_space(1))) unsigned int*)g,
                                     (__attribute__((address_space(3))) unsigned int*)l,
                                     16, 0, 0);
}

__global__ __launch_bounds__(256) void mmd_mfma(const ushort* __restrict__ hi,
                                                const ushort* __restrict__ lo,
                                                const float* __restrict__ sq,
                                                const float* __restrict__ negc,
                                                double* __restrict__ accum) {
    __shared__ ushort As[2][TILE * BK];   // 2 x 8 KB
    __shared__ ushort Bs[2][TILE * BK];   // 2 x 8 KB  (total 32 KB)
    __shared__ float wsum[4];

    // T1: XCD swizzle (2080 % 8 == 0 -> bijective), then triangle decode
    int b  = blockIdx.x;
    int bs = (b & 7) * (NTRI / 8) + (b >> 3);
    int it = 0, cum = 0;
    while (cum + (NTILE - it) <= bs) { cum += NTILE - it; ++it; }
    int jt = it + (bs - cum);

    int tid = threadIdx.x, lane = tid & 63, wid = tid >> 6;
    int wrow = wid >> 1, wcol = wid & 1;      // 2x2 wave grid; per-wave 64x64
    int rowA = it * TILE, rowB = jt * TILE;
    int rsel = lane & 15, ksel = lane >> 4;

    const ushort* Ap[3] = {hi, hi, lo};
    const ushort* Bp[3] = {hi, lo, hi};

    f32x4 acc[4][4] = {};

    // stage K-step kt into buffer buf. A-tile = 128x32 bf16 = 512 16B-chunks.
    // LDS dest linear; global source column pre-swizzled (rule #21):
    // physical slot sl at row r holds global slot sl ^ ((r>>1)&3).
    auto STAGE = [&](int kt, int buf) {
        int p = kt >> 3, kc = (kt & 7) * BK;
        const ushort* Asrc = Ap[p];
        const ushort* Bsrc = Bp[p];
        #pragma unroll
        for (int lg = 0; lg < 2; ++lg) {
            int ci0 = lg * 256 + wid * 64;    // wave-uniform 16B-chunk base
            int ci  = ci0 + lane;
            int r   = ci >> 2;                // tile row 0..127
            int sl  = ci & 3;                 // physical 16B slot 0..3
            int slin = sl ^ ((r >> 1) & 3);   // pre-swizzled global slot
            gload_lds16(Asrc + (size_t)(rowA + r) * D_DIM + kc + slin * 8,
                        &As[buf][ci0 * 8]);
            gload_lds16(Bsrc + (size_t)(rowB + r) * D_DIM + kc + slin * 8,
                        &Bs[buf][ci0 * 8]);
        }
    };

    STAGE(0, 0);
    asm volatile("s_waitcnt vmcnt(0)" ::: "memory");
    __syncthreads();

    #pragma unroll 1
    for (int kt = 0; kt < 24; ++kt) {
        int buf = kt & 1;
        if (kt + 1 < 24) STAGE(kt + 1, buf ^ 1);   // issue next tile early

        s16x8 af[4], bf[4];
        #pragma unroll
        for (int m = 0; m < 4; ++m) {
            int r  = wrow * 64 + m * 16 + rsel;
            int sp = ksel ^ ((r >> 1) & 3);        // T2 swizzled read slot
            af[m] = *(const s16x8*)&As[buf][r * BK + sp * 8];
        }
        #pragma unroll
        for (int n = 0; n < 4; ++n) {
            int r  = wcol * 64 + n * 16 + rsel;
            int sp = ksel ^ ((r >> 1) & 3);
            bf[n] = *(const s16x8*)&Bs[buf][r * BK + sp * 8];
        }
        __builtin_amdgcn_s_setprio(1);             // T5
        #pragma unroll
        for (int m = 0; m < 4; ++m)
            #pragma unroll
            for (int n = 0; n < 4; ++n)
                acc[m][n] = __builtin_amdgcn_mfma_f32_16x16x32_bf16(af[m], bf[n], acc[m][n], 0, 0, 0);
        __builtin_amdgcn_s_setprio(0);

        asm volatile("s_waitcnt vmcnt(0)" ::: "memory");  // staged tile landed
        __syncthreads();                                   // one barrier per K-step
    }

    // fused epilogue: d2 -> 5-kernel sum, in-register
    float nc = *negc;
    float sqj[4];
    #pragma unroll
    for (int n = 0; n < 4; ++n)
        sqj[n] = sq[rowB + wcol * 64 + n * 16 + rsel];
    float tsum = 0.f;
    #pragma unroll
    for (int m = 0; m < 4; ++m) {
        #pragma unroll
        for (int r = 0; r < 4; ++r) {
            float si = sq[rowA + wrow * 64 + m * 16 + ksel * 4 + r];
            #pragma unroll
            for (int n = 0; n < 4; ++n) {
                float d2 = fmaxf(si + sqj[n] - 2.0f * acc[m][n][r], 0.f);
                float u  = exp2f(nc * d2);
                float u2 = u * u, u4 = u2 * u2, u8 = u4 * u4;
                tsum += u + u2 + u4 + u8 + u8 * u8;
            }
        }
    }
    float scale = (((it < 32) == (jt < 32)) ? 1.f : -1.f) * ((it == jt) ? 1.f : 2.f);
    tsum *= scale;

    #pragma unroll
    for (int off = 32; off; off >>= 1) tsum += __shfl_down(tsum, off, 64);
    if (lane == 0) wsum[wid] = tsum;
    __syncthreads();
    if (tid == 0) {
        float t = wsum[0] + wsum[1] + wsum[2] + wsum[3];
        atomicAdd(accum, (double)t);
    }
}

__global__ void finalize_kernel(const double* __restrict__ accum, float* __restrict__ out) {
    out[0] = (float)(accum[0] / ((double)B_HALF * (double)B_HALF));
}

extern "C" void kernel_launch(void* const* d_in, const int* in_sizes, int n_in,
                              void* d_out, int out_size, void* d_ws, size_t ws_size,
                              hipStream_t stream) {
    const float* src = (const float*)d_in[0];
    const float* tgt = (const float*)d_in[1];
    float* out = (float*)d_out;

    char* ws = (char*)d_ws;
    float*  sq      = (float*)ws;                         // 32 KB
    float*  colpart = (float*)(ws + 32768);               // 64 KB (64 x 256)
    float*  negc    = (float*)(ws + 98304);
    double* accum   = (double*)(ws + 98312);
    ushort* hi      = (ushort*)(ws + 131072);             // 4 MB
    ushort* lo      = (ushort*)(ws + 131072 + (size_t)N_TOTAL * D_DIM * 2);  // 4 MB

    prep_kernel<<<N_TOTAL / 4, 256, 0, stream>>>(src, tgt, hi, lo, sq);
    colpart_kernel<<<64, 256, 0, stream>>>(src, tgt, colpart);
    bw_kernel<<<1, 256, 0, stream>>>(sq, colpart, negc, accum);
    mmd_mfma<<<NTRI, 256, 0, stream>>>(hi, lo, sq, negc, accum);
    finalize_kernel<<<1, 1, 0, stream>>>(accum, out);
}

// Round 6
// 113.111 us; speedup vs baseline: 1.1060x; 1.0151x over previous
//
#include <hip/hip_runtime.h>
#include <hip/hip_bf16.h>

// MMD loss via bf16 hi/lo-split MFMA Gram pass — plane-fused K-chunks.
//   dot ~= hi.hi + hi.lo + lo.hi ; per K-chunk stage {A_hi,A_lo,B_hi,B_lo}
//   once and run all 3 plane-products (LDS traffic -33%, barriers 24->8).
//   mfma_f32_32x32x16_bf16 (higher rate, 4x fewer instructions).
// 128^2 tile, 4 waves (2x2 of 64x64), BK=32, dbuf 64KB (2 blocks/CU),
// T2 swizzle sp=s^((r>>1)&3) both-sides, T1 XCD swizzle, T5 setprio.

#define N_TOTAL 8192
#define B_HALF 4096
#define D_DIM 256
#define TILE 128
#define NTILE 64          // 8192/128
#define NTRI 2080         // 64*65/2
#define BK 32
#define NCHUNK 8          // 256/32

typedef float f32x16 __attribute__((ext_vector_type(16)));
typedef short s16x8 __attribute__((ext_vector_type(8)));

__device__ __forceinline__ const float* row_base(const float* src, const float* tgt, int r) {
    return (r < B_HALF) ? src + (size_t)r * D_DIM : tgt + (size_t)(r - B_HALF) * D_DIM;
}

// fused split (hi/lo bf16) + row sq. one wave per row, 4 rows/block.
__global__ __launch_bounds__(256) void prep_kernel(const float* __restrict__ src,
                                                   const float* __restrict__ tgt,
                                                   ushort* __restrict__ hi,
                                                   ushort* __restrict__ lo,
                                                   float* __restrict__ sq) {
    int w = threadIdx.x >> 6, lane = threadIdx.x & 63;
    int row = blockIdx.x * 4 + w;
    const float* rp = row_base(src, tgt, row);
    float4 v = ((const float4*)rp)[lane];
    float f[4] = {v.x, v.y, v.z, v.w};
    ushort h[4], l[4];
    #pragma unroll
    for (int e = 0; e < 4; ++e) {
        __hip_bfloat16 hb = __float2bfloat16(f[e]);
        float hf = __bfloat162float(hb);
        __hip_bfloat16 lb = __float2bfloat16(f[e] - hf);
        h[e] = *(ushort*)&hb;
        l[e] = *(ushort*)&lb;
    }
    size_t base = (size_t)row * D_DIM + lane * 4;
    *(ushort4*)(hi + base) = *(ushort4*)h;
    *(ushort4*)(lo + base) = *(ushort4*)l;
    float s = f[0]*f[0] + f[1]*f[1] + f[2]*f[2] + f[3]*f[3];
    #pragma unroll
    for (int off = 32; off; off >>= 1) s += __shfl_down(s, off, 64);
    if (lane == 0) sq[row] = s;
}

// per-block partial column sums (no atomics)
__global__ __launch_bounds__(256) void colpart_kernel(const float* __restrict__ src,
                                                      const float* __restrict__ tgt,
                                                      float* __restrict__ colpart) {
    int t  = threadIdx.x;
    int r0 = blockIdx.x * 128;
    float s = 0.f;
    for (int r = r0; r < r0 + 128; ++r)
        s += row_base(src, tgt, r)[t];
    colpart[blockIdx.x * D_DIM + t] = s;
}

__global__ __launch_bounds__(256) void bw_kernel(const float* __restrict__ sq,
                                                 const float* __restrict__ colpart,
                                                 float* __restrict__ negc,
                                                 double* __restrict__ accum) {
    __shared__ double red[256];
    int t = threadIdx.x;
    double s = 0.0;
    for (int i = t; i < N_TOTAL; i += 256) s += (double)sq[i];
    red[t] = s;
    __syncthreads();
    for (int off = 128; off; off >>= 1) {
        if (t < off) red[t] += red[t + off];
        __syncthreads();
    }
    double sumsq = red[0];
    __syncthreads();
    float c = 0.f;
    for (int k = 0; k < 64; ++k) c += colpart[k * D_DIM + t];
    red[t] = (double)c * (double)c;
    __syncthreads();
    for (int off = 128; off; off >>= 1) {
        if (t < off) red[t] += red[t + off];
        __syncthreads();
    }
    if (t == 0) {
        double S1 = 2.0 * (double)N_TOTAL * sumsq - 2.0 * red[0];
        double nn = (double)N_TOTAL * (double)N_TOTAL - (double)N_TOTAL;
        double bw = S1 / nn / 4.0;    // KERNEL_MUL^(KERNEL_NUM//2) = 4
        negc[0] = (float)(-1.4426950408889634 / (16.0 * bw));
        accum[0] = 0.0;
    }
}

__device__ __forceinline__ void gload_lds16(const void* g, void* l) {
    __builtin_amdgcn_global_load_lds((const __attribute__((address_space(1))) unsigned int*)g,
                                     (__attribute__((address_space(3))) unsigned int*)l,
                                     16, 0, 0);
}

__global__ __launch_bounds__(256, 2) void mmd_mfma(const ushort* __restrict__ hi,
                                                   const ushort* __restrict__ lo,
                                                   const float* __restrict__ sq,
                                                   const float* __restrict__ negc,
                                                   double* __restrict__ accum) {
    // [buf][tile: 0=A_hi 1=A_lo 2=B_hi 3=B_lo][128 rows x 32 k]  = 64 KB
    __shared__ ushort lds[2][4][TILE * BK];
    __shared__ float wsum[4];

    // T1: XCD swizzle (2080 % 8 == 0 -> bijective), then triangle decode
    int b  = blockIdx.x;
    int bs = (b & 7) * (NTRI / 8) + (b >> 3);
    int it = 0, cum = 0;
    while (cum + (NTILE - it) <= bs) { cum += NTILE - it; ++it; }
    int jt = it + (bs - cum);

    int tid = threadIdx.x, lane = tid & 63, wid = tid >> 6;
    int wrow = wid >> 1, wcol = wid & 1;      // 2x2 wave grid; per-wave 64x64
    int rowA = it * TILE, rowB = jt * TILE;
    int c32 = lane & 31, khalf = lane >> 5;

    const ushort* srcs[4] = { hi + (size_t)rowA * D_DIM, lo + (size_t)rowA * D_DIM,
                              hi + (size_t)rowB * D_DIM, lo + (size_t)rowB * D_DIM };

    f32x16 acc[2][2] = {};

    // stage chunk kt (all 4 tiles) into buffer buf. Linear LDS dest; global
    // source column pre-swizzled (rule #21): phys slot sl holds sl^((r>>1)&3).
    auto STAGE = [&](int kt, int buf) {
        int kc = kt * BK;
        #pragma unroll
        for (int t = 0; t < 4; ++t) {
            #pragma unroll
            for (int lg = 0; lg < 2; ++lg) {
                int ci0 = lg * 256 + wid * 64;    // wave-uniform 16B-chunk base
                int ci  = ci0 + lane;
                int r   = ci >> 2;                // tile row 0..127
                int sl  = ci & 3;                 // physical 16B slot 0..3
                int slin = sl ^ ((r >> 1) & 3);
                gload_lds16(srcs[t] + (size_t)r * D_DIM + kc + slin * 8,
                            &lds[buf][t][ci0 * 8]);
            }
        }
    };

    STAGE(0, 0);
    asm volatile("s_waitcnt vmcnt(0)" ::: "memory");
    __syncthreads();

    #pragma unroll 1
    for (int kt = 0; kt < NCHUNK; ++kt) {
        int buf = kt & 1;
        if (kt + 1 < NCHUNK) STAGE(kt + 1, buf ^ 1);   // issue next chunk early

        #pragma unroll
        for (int kap = 0; kap < 2; ++kap) {            // two K=16 steps in BK=32
            int s = kap * 2 + khalf;                   // logical 16B slot
            s16x8 ah[2], al[2], bh[2], bl[2];
            #pragma unroll
            for (int mt = 0; mt < 2; ++mt) {
                int r  = wrow * 64 + mt * 32 + c32;
                int sp = s ^ ((r >> 1) & 3);           // T2 swizzled read
                ah[mt] = *(const s16x8*)&lds[buf][0][r * BK + sp * 8];
                al[mt] = *(const s16x8*)&lds[buf][1][r * BK + sp * 8];
            }
            #pragma unroll
            for (int nt = 0; nt < 2; ++nt) {
                int r  = wcol * 64 + nt * 32 + c32;
                int sp = s ^ ((r >> 1) & 3);
                bh[nt] = *(const s16x8*)&lds[buf][2][r * BK + sp * 8];
                bl[nt] = *(const s16x8*)&lds[buf][3][r * BK + sp * 8];
            }
            __builtin_amdgcn_s_setprio(1);             // T5
            #pragma unroll
            for (int mt = 0; mt < 2; ++mt)
                #pragma unroll
                for (int nt = 0; nt < 2; ++nt) {
                    acc[mt][nt] = __builtin_amdgcn_mfma_f32_32x32x16_bf16(ah[mt], bh[nt], acc[mt][nt], 0, 0, 0);
                    acc[mt][nt] = __builtin_amdgcn_mfma_f32_32x32x16_bf16(ah[mt], bl[nt], acc[mt][nt], 0, 0, 0);
                    acc[mt][nt] = __builtin_amdgcn_mfma_f32_32x32x16_bf16(al[mt], bh[nt], acc[mt][nt], 0, 0, 0);
                }
            __builtin_amdgcn_s_setprio(0);
        }

        asm volatile("s_waitcnt vmcnt(0)" ::: "memory");  // next chunk landed
        __syncthreads();                                   // one barrier per chunk
    }

    // fused epilogue: d2 -> 5-kernel sum. C/D: col=lane&31, row=(reg&3)+8*(reg>>2)+4*khalf
    float nc = *negc;
    float sjn[2];
    #pragma unroll
    for (int nt = 0; nt < 2; ++nt)
        sjn[nt] = sq[rowB + wcol * 64 + nt * 32 + c32];
    float tsum = 0.f;
    #pragma unroll
    for (int mt = 0; mt < 2; ++mt) {
        #pragma unroll
        for (int reg = 0; reg < 16; ++reg) {
            int i = rowA + wrow * 64 + mt * 32 + (reg & 3) + 8 * (reg >> 2) + 4 * khalf;
            float si = sq[i];
            #pragma unroll
            for (int nt = 0; nt < 2; ++nt) {
                float d2 = fmaxf(si + sjn[nt] - 2.0f * acc[mt][nt][reg], 0.f);
                float u  = exp2f(nc * d2);
                float u2 = u * u, u4 = u2 * u2, u8 = u4 * u4;
                tsum += u + u2 + u4 + u8 + u8 * u8;
            }
        }
    }
    float scale = (((it < 32) == (jt < 32)) ? 1.f : -1.f) * ((it == jt) ? 1.f : 2.f);
    tsum *= scale;

    #pragma unroll
    for (int off = 32; off; off >>= 1) tsum += __shfl_down(tsum, off, 64);
    if (lane == 0) wsum[wid] = tsum;
    __syncthreads();
    if (tid == 0) {
        float t = wsum[0] + wsum[1] + wsum[2] + wsum[3];
        atomicAdd(accum, (double)t);
    }
}

__global__ void finalize_kernel(const double* __restrict__ accum, float* __restrict__ out) {
    out[0] = (float)(accum[0] / ((double)B_HALF * (double)B_HALF));
}

extern "C" void kernel_launch(void* const* d_in, const int* in_sizes, int n_in,
                              void* d_out, int out_size, void* d_ws, size_t ws_size,
                              hipStream_t stream) {
    const float* src = (const float*)d_in[0];
    const float* tgt = (const float*)d_in[1];
    float* out = (float*)d_out;

    char* ws = (char*)d_ws;
    float*  sq      = (float*)ws;                         // 32 KB
    float*  colpart = (float*)(ws + 32768);               // 64 KB (64 x 256)
    float*  negc    = (float*)(ws + 98304);
    double* accum   = (double*)(ws + 98312);
    ushort* hi      = (ushort*)(ws + 131072);             // 4 MB
    ushort* lo      = (ushort*)(ws + 131072 + (size_t)N_TOTAL * D_DIM * 2);  // 4 MB

    prep_kernel<<<N_TOTAL / 4, 256, 0, stream>>>(src, tgt, hi, lo, sq);
    colpart_kernel<<<64, 256, 0, stream>>>(src, tgt, colpart);
    bw_kernel<<<1, 256, 0, stream>>>(sq, colpart, negc, accum);
    mmd_mfma<<<NTRI, 256, 0, stream>>>(hi, lo, sq, negc, accum);
    finalize_kernel<<<1, 1, 0, stream>>>(accum, out);
}